// Round 11
// baseline (252.574 us; speedup 1.0000x reference)
//
#include <hip/hip_runtime.h>

// Fully-fused CIN (16x16x32 MFMA, HW-verified layouts).
//   Y_hh[o,d] = sum_m W[o,hh,m] * x0[b,m,d]      (MFMA, 3-term bf16 split)
//   h_next[o,d] = relu(bias[o] + sum_hh h[hh,d] * Y_hh[o,d])
// Round-9: ONE 1024-thread block (16 waves) per b; wave = (o-frag f, k-half).
// Each wave runs half the hh range; partials combine through the dead LDS h
// buffer (2 extra barriers/layer). Guarantees 16 waves/CU = 4 waves/SIMD
// (round-8 evidence: only one 8-wave block was resident -> 2 waves/SIMD ->
// MFMA pipe idle 45%). A-fragment traffic unchanged (each frag read once).
// B=512, M=32, D=64, O=128/layer, H = 32/128/128.

constexpr int Bb = 512, Mm = 32, Dd = 64, Oo = 128;

typedef __attribute__((ext_vector_type(8))) short bf16x8;
typedef __attribute__((ext_vector_type(4))) float f32x4;

static __device__ __forceinline__ ushort f2bf(float f) {
  union { float f; uint u; } v;
  v.f = f;
  uint u = v.u;
  return (ushort)((u + 0x7FFFu + ((u >> 16) & 1u)) >> 16);  // RNE
}
static __device__ __forceinline__ float bf2f(ushort b) {
  union { uint u; float f; } v;
  v.u = (uint)b << 16;
  return v.f;
}

// W[o][hh*32+m] -> A-frag planes [hh][f][lane][j]: o=f*16+(lane&15), m=(lane>>4)*8+j
static __device__ __forceinline__ void wsplit_one(const float* __restrict__ W,
                                                  ushort* __restrict__ Whi,
                                                  ushort* __restrict__ Wlo,
                                                  int H, int t) {
  int l = t & 63, fo = (t >> 6) & 7, hh = t >> 9;
  int o = fo * 16 + (l & 15);
  int m0 = (l >> 4) * 8;
  const float* src = W + (size_t)o * (H * 32) + hh * 32 + m0;
  ushort hi[8], lo[8];
#pragma unroll
  for (int j = 0; j < 8; ++j) {
    float w = src[j];
    ushort h = f2bf(w);
    hi[j] = h;
    lo[j] = f2bf(w - bf2f(h));
  }
  *reinterpret_cast<uint4*>(Whi + (size_t)t * 8) = *reinterpret_cast<uint4*>(hi);
  *reinterpret_cast<uint4*>(Wlo + (size_t)t * 8) = *reinterpret_cast<uint4*>(lo);
}

// x0[b][m][d] -> B-frag planes [b][fd][lane][j]: m=(lane>>4)*8+j, d=fd*16+(lane&15)
static __device__ __forceinline__ void x0split_one(const float* __restrict__ x0,
                                                   ushort* __restrict__ Xhi,
                                                   ushort* __restrict__ Xlo, int t) {
  int l = t & 63, fd = (t >> 6) & 3, b = t >> 8;
  int d = fd * 16 + (l & 15);
  int m0 = (l >> 4) * 8;
  const float* src = x0 + ((size_t)b * Mm + m0) * Dd + d;
  ushort hi[8], lo[8];
#pragma unroll
  for (int j = 0; j < 8; ++j) {
    float w = src[j * Dd];
    ushort h = f2bf(w);
    hi[j] = h;
    lo[j] = f2bf(w - bf2f(h));
  }
  *reinterpret_cast<uint4*>(Xhi + (size_t)t * 8) = *reinterpret_cast<uint4*>(hi);
  *reinterpret_cast<uint4*>(Xlo + (size_t)t * 8) = *reinterpret_cast<uint4*>(lo);
}

__global__ __launch_bounds__(256) void prep_kernel(
    const float* __restrict__ W0, const float* __restrict__ W1,
    const float* __restrict__ W2, const float* __restrict__ x0,
    ushort* __restrict__ Whi0, ushort* __restrict__ Wlo0,
    ushort* __restrict__ Whi1, ushort* __restrict__ Wlo1,
    ushort* __restrict__ Whi2, ushort* __restrict__ Wlo2,
    ushort* __restrict__ Xhi, ushort* __restrict__ Xlo) {
  int t = blockIdx.x * 256 + threadIdx.x;
  if (t < 16384) {
    wsplit_one(W0, Whi0, Wlo0, 32, t);
  } else if (t < 81920) {
    wsplit_one(W1, Whi1, Wlo1, 128, t - 16384);
  } else if (t < 147456) {
    wsplit_one(W2, Whi2, Wlo2, 128, t - 81920);
  } else {
    x0split_one(x0, Xhi, Xlo, t - 147456);
  }
}

// Core MFMA loop over HW hh-steps (this wave's half of the layer's K range).
// hsrc already offset to this wave's first hh; pwh/pwl pre-offset to (hh0, f).
template <int HW>
static __device__ __forceinline__ void mfma_loop(
    const float* __restrict__ hsrc,
    const ushort* __restrict__ pwh, const ushort* __restrict__ pwl,
    const bf16x8 (&xh)[4], const bf16x8 (&xl)[4], int cid, f32x4 (&acc)[4]) {
  const size_t hstride = (size_t)8 * 64 * 8;  // ushorts per hh
  const f32x4 kZ = {0.f, 0.f, 0.f, 0.f};

  bf16x8 Ah[3], Al[3];
#pragma unroll
  for (int j = 0; j < 3; ++j) {
    Ah[j] = *reinterpret_cast<const bf16x8*>(pwh + (size_t)j * hstride);
    Al[j] = *reinterpret_cast<const bf16x8*>(pwl + (size_t)j * hstride);
  }
  float hvc[4];
#pragma unroll
  for (int fd = 0; fd < 4; ++fd) hvc[fd] = hsrc[fd * 16 + cid];

#pragma unroll 1
  for (int hh3 = 0; hh3 < HW; hh3 += 3) {
#pragma unroll
    for (int j = 0; j < 3; ++j) {
      const int hh = hh3 + j;
      if (HW % 3 != 0 && hh >= HW) break;
      const int hn1 = (hh + 1 < HW) ? hh + 1 : HW - 1;
      float nhv[4];
#pragma unroll
      for (int fd = 0; fd < 4; ++fd) nhv[fd] = hsrc[hn1 * 64 + fd * 16 + cid];

      f32x4 y[4];
#pragma unroll
      for (int fd = 0; fd < 4; ++fd)
        y[fd] = __builtin_amdgcn_mfma_f32_16x16x32_bf16(Ah[j], xh[fd], kZ, 0, 0, 0);
#pragma unroll
      for (int fd = 0; fd < 4; ++fd)
        y[fd] = __builtin_amdgcn_mfma_f32_16x16x32_bf16(Ah[j], xl[fd], y[fd], 0, 0, 0);
#pragma unroll
      for (int fd = 0; fd < 4; ++fd)
        y[fd] = __builtin_amdgcn_mfma_f32_16x16x32_bf16(Al[j], xh[fd], y[fd], 0, 0, 0);

      const int hn3 = (hh + 3 < HW) ? hh + 3 : HW - 1;
      Ah[j] = *reinterpret_cast<const bf16x8*>(pwh + (size_t)hn3 * hstride);
      Al[j] = *reinterpret_cast<const bf16x8*>(pwl + (size_t)hn3 * hstride);

#pragma unroll
      for (int fd = 0; fd < 4; ++fd)
#pragma unroll
        for (int r = 0; r < 4; ++r) acc[fd][r] = fmaf(hvc[fd], y[fd][r], acc[fd][r]);
#pragma unroll
      for (int fd = 0; fd < 4; ++fd) hvc[fd] = nhv[fd];
    }
  }
}

// One layer: both k-half waves run mfma_loop over their range; kh=1 dumps raw
// acc into h_next's f-region; kh=0 combines, applies bias+relu, writes h_next
// (unless !WRITE_H) and folds the d-sum into score.
template <int H, bool WRITE_H>
static __device__ __forceinline__ void layer(
    const float* __restrict__ h_src, float* __restrict__ h_next,
    const ushort* __restrict__ Whi, const ushort* __restrict__ Wlo,
    const float* __restrict__ bias, const float* __restrict__ lw,
    const bf16x8 (&xh)[4], const bf16x8 (&xl)[4],
    int f, int kh, int lane, float& score) {
  const int cid = lane & 15;
  const int rg = lane >> 4;
  const int hh0 = kh * (H / 2);

  f32x4 acc[4];
#pragma unroll
  for (int fd = 0; fd < 4; ++fd) acc[fd] = (f32x4){0.f, 0.f, 0.f, 0.f};

  const ushort* pwh = Whi + (((size_t)hh0 * 8 + f) * 64 + lane) * 8;
  const ushort* pwl = Wlo + (((size_t)hh0 * 8 + f) * 64 + lane) * 8;
  mfma_loop<H / 2>(h_src + hh0 * 64, pwh, pwl, xh, xl, cid, acc);

  if (kh) {  // dump raw partial acc into h_next's f-region (dead until combine)
#pragma unroll
    for (int r = 0; r < 4; ++r)
#pragma unroll
      for (int fd = 0; fd < 4; ++fd)
        h_next[(f * 16 + rg * 4 + r) * 64 + fd * 16 + cid] = acc[fd][r];
  }
  __syncthreads();
  if (!kh) {
#pragma unroll
    for (int r = 0; r < 4; ++r) {
      const int o = f * 16 + rg * 4 + r;
      const float bs = bias[o];
      float sd = 0.f;
#pragma unroll
      for (int fd = 0; fd < 4; ++fd) {
        float v = acc[fd][r] + h_next[o * 64 + fd * 16 + cid] + bs;
        v = v > 0.f ? v : 0.f;
        if (WRITE_H) h_next[o * 64 + fd * 16 + cid] = v;
        sd += v;
      }
#pragma unroll
      for (int mk = 1; mk < 16; mk <<= 1) sd += __shfl_xor(sd, mk, 64);
      if (cid == 0) score = fmaf(sd, lw[o], score);
    }
  }
  __syncthreads();
}

__global__ __launch_bounds__(1024, 4) void cin_fused_kernel(
    const float* __restrict__ x0,
    const ushort* __restrict__ Whi0, const ushort* __restrict__ Wlo0,
    const ushort* __restrict__ Whi1, const ushort* __restrict__ Wlo1,
    const ushort* __restrict__ Whi2, const ushort* __restrict__ Wlo2,
    const ushort* __restrict__ Xhi, const ushort* __restrict__ Xlo,
    const float* __restrict__ b0, const float* __restrict__ b1,
    const float* __restrict__ b2, const float* __restrict__ lw,
    const float* __restrict__ lb, float* __restrict__ out) {
  __shared__ float hA[Oo * Dd];  // 32 KB: x0 (L0 in), then L1 out (L2 in)
  __shared__ float hB[Oo * Dd];  // 32 KB: L0 out (L1 in), then L2 scratch+sred
  // total LDS = 65536 B

  const int b = blockIdx.x;
  const int t = threadIdx.x;
  const int lane = t & 63;
  const int w = __builtin_amdgcn_readfirstlane(t >> 6);  // 16 waves
  const int f = w & 7;    // o-frag
  const int kh = w >> 3;  // k-half

  // x0 B-fragments, register-resident throughout
  bf16x8 xh[4], xl[4];
#pragma unroll
  for (int fd = 0; fd < 4; ++fd) {
    size_t off = (((size_t)b * 4 + fd) * 64 + lane) * 8;
    xh[fd] = *reinterpret_cast<const bf16x8*>(Xhi + off);
    xl[fd] = *reinterpret_cast<const bf16x8*>(Xlo + off);
  }

  // stage x0[b] (32x64 f32 = 512 float4) into hA
  if (t < 512)
    reinterpret_cast<float4*>(hA)[t] =
        reinterpret_cast<const float4*>(x0 + (size_t)b * Mm * Dd)[t];
  __syncthreads();

  float score = 0.f;
  layer<32, true>(hA, hB, Whi0, Wlo0, b0, lw, xh, xl, f, kh, lane, score);
  layer<128, true>(hB, hA, Whi1, Wlo1, b1, lw + 128, xh, xl, f, kh, lane, score);
  layer<128, false>(hA, hB, Whi2, Wlo2, b2, lw + 256, xh, xl, f, kh, lane, score);

  // block-wide score reduction (hB scratch dead; layer() ended with a barrier)
#pragma unroll
  for (int mk = 1; mk < 64; mk <<= 1) score += __shfl_xor(score, mk, 64);
  if (lane == 0 && kh == 0) hB[f] = score;
  __syncthreads();
  if (t == 0) {
    float tot = 0.f;
#pragma unroll
    for (int i = 0; i < 8; ++i) tot += hB[i];
    out[b] = tot + lb[0];
  }
}

extern "C" void kernel_launch(void* const* d_in, const int* in_sizes, int n_in,
                              void* d_out, int out_size, void* d_ws, size_t ws_size,
                              hipStream_t stream) {
  const float* x0 = (const float*)d_in[0];
  const float* W0 = (const float*)d_in[1];
  const float* b0 = (const float*)d_in[2];
  const float* W1 = (const float*)d_in[3];
  const float* b1 = (const float*)d_in[4];
  const float* W2 = (const float*)d_in[5];
  const float* b2 = (const float*)d_in[6];
  const float* lw = (const float*)d_in[7];
  const float* lb = (const float*)d_in[8];
  float* out = (float*)d_out;

  // workspace: only the split planes
  ushort* Whi0 = (ushort*)d_ws;
  ushort* Wlo0 = Whi0 + (size_t)32 * 8 * 64 * 8;
  ushort* Whi1 = Wlo0 + (size_t)32 * 8 * 64 * 8;
  ushort* Wlo1 = Whi1 + (size_t)128 * 8 * 64 * 8;
  ushort* Whi2 = Wlo1 + (size_t)128 * 8 * 64 * 8;
  ushort* Wlo2 = Whi2 + (size_t)128 * 8 * 64 * 8;
  ushort* Xhi = Wlo2 + (size_t)128 * 8 * 64 * 8;
  ushort* Xlo = Xhi + (size_t)Bb * 4 * 64 * 8;

  prep_kernel<<<dim3(1088), dim3(256), 0, stream>>>(W0, W1, W2, x0, Whi0, Wlo0,
                                                    Whi1, Wlo1, Whi2, Wlo2, Xhi, Xlo);

  cin_fused_kernel<<<dim3(Bb), dim3(1024), 0, stream>>>(
      x0, Whi0, Wlo0, Whi1, Wlo1, Whi2, Wlo2, Xhi, Xlo, b0, b1, b2, lw, lb, out);
}